// Round 7
// baseline (230.649 us; speedup 1.0000x reference)
//
#include <hip/hip_runtime.h>

#define N_ROWS 65536
#define DIM    256
#define KCODES 1024
#define TAU    2e-4f

typedef _Float16 half8 __attribute__((ext_vector_type(8)));
typedef _Float16 half4_t __attribute__((ext_vector_type(4)));
typedef float f32x4  __attribute__((ext_vector_type(4)));

__device__ __forceinline__ void gll16(const void* g, void* l) {
    __builtin_amdgcn_global_load_lds((const __attribute__((address_space(1))) void*)g,
                                     (__attribute__((address_space(3))) void*)l, 16, 0, 0);
}

__device__ __forceinline__ half8 cvt8(float4 x, float4 y) {
    half8 h;
    h[0] = (_Float16)x.x; h[1] = (_Float16)x.y; h[2] = (_Float16)x.z; h[3] = (_Float16)x.w;
    h[4] = (_Float16)y.x; h[5] = (_Float16)y.y; h[6] = (_Float16)y.z; h[7] = (_Float16)y.w;
    return h;
}

// ============ kernel 1: row/code norms + f16 codebook ============
__global__ __launch_bounds__(256) void vq_prep(const float* __restrict__ z,
                                               const float* __restrict__ cbk,
                                               _Float16* __restrict__ B2,
                                               float* __restrict__ rn,
                                               float* __restrict__ cn) {
    int gid = blockIdx.x * 256 + threadIdx.x;
    int row = gid >> 6;
    int l   = gid & 63;
    if (row < N_ROWS) {
        float4 v = ((const float4*)(z + (size_t)row * DIM))[l];
        float s = v.x*v.x + v.y*v.y + v.z*v.z + v.w*v.w;
        #pragma unroll
        for (int m = 32; m; m >>= 1) s += __shfl_xor(s, m, 64);
        if (l == 0) rn[row] = s;
    } else {
        int c = row - N_ROWS;
        float4 v = ((const float4*)(cbk + (size_t)c * DIM))[l];
        float s = v.x*v.x + v.y*v.y + v.z*v.z + v.w*v.w;
        #pragma unroll
        for (int m = 32; m; m >>= 1) s += __shfl_xor(s, m, 64);
        if (l == 0) cn[c] = s;
        half4_t h;
        h.x = (_Float16)v.x; h.y = (_Float16)v.y;
        h.z = (_Float16)v.z; h.w = (_Float16)v.w;
        *(half4_t*)(B2 + (size_t)c * DIM + l * 4) = h;
    }
}

// ============ kernel 2: f16 MFMA GEMM, A-in-registers from f32 z ============
// block = 4 waves; wave tile = 64 rows x 128 codes; K'=256; B tile (64KB) staged
// once in LDS (swizzled), zero barriers in K-loop; u64-packed top-2 epilogue.
__global__ __launch_bounds__(256, 2) void vq_gemm3(const float* __restrict__ z,
                                                   const _Float16* __restrict__ B2,
                                                   const float* __restrict__ rn,
                                                   const float* __restrict__ cn,
                                                   ulonglong2* __restrict__ part) {
    __shared__ __align__(16) _Float16 Bs[4 * 128 * 64];   // 64 KB, [stage4][code][64k]

    int bid = blockIdx.x;
    int ctile = (bid >> 3) & 7;                 // same-XCD bids share rtile -> A panel L2-hot
    int rtile = (bid & 7) | ((bid >> 6) << 3);  // 0..255
    int tid = threadIdx.x;
    int wid = tid >> 6;
    int l   = tid & 63;
    int li  = l & 15, lg = l >> 4;
    int lrow  = l >> 3;
    int lcolb = ((l & 7) ^ lrow) << 4;          // proven R6 source pre-swizzle
    int swz   = (li & 7) << 4;                  // read-side swizzle (row&7 == li&7)

    const size_t arow0 = (size_t)rtile * 256;
    const size_t ccol0 = (size_t)ctile * 128;

    // stage full B tile: 4 stages x 4 gll16 per wave (each 1KB wave-wide)
    const char* gb = (const char*)B2 + ccol0 * 512;    // B2 row = 512B
    #pragma unroll
    for (int s4 = 0; s4 < 4; ++s4)
        #pragma unroll
        for (int jj = 0; jj < 4; ++jj) {
            int r = wid * 32 + jj * 8 + lrow;
            gll16(gb + (size_t)r * 512 + s4 * 128 + lcolb,
                  (char*)Bs + s4 * 16384 + (wid * 32 + jj * 8) * 128 + l * 16);
        }

    // epilogue operands (hide under staging)
    float cnv[8];
    #pragma unroll
    for (int ct = 0; ct < 8; ++ct) cnv[ct] = cn[ccol0 + ct*16 + li];
    float rv[4][4];
    #pragma unroll
    for (int rt = 0; rt < 4; ++rt)
        #pragma unroll
        for (int q = 0; q < 4; ++q)
            rv[rt][q] = rn[arow0 + wid*64 + rt*16 + lg*4 + q];

    // A: private rows, direct from f32 z, reg-staged with 1-stage lookahead
    const float* abase = z + arow0 * DIM;
    float4 a0[4], a1[4];
    #pragma unroll
    for (int rt = 0; rt < 4; ++rt) {
        const float4* ap = (const float4*)(abase + (size_t)(wid*64 + rt*16 + li) * DIM + lg*8);
        a0[rt] = ap[0]; a1[rt] = ap[1];
    }

    __syncthreads();   // one-time drain: B tile + stage-0 A loads

    f32x4 acc[4][8];
    #pragma unroll
    for (int rt = 0; rt < 4; ++rt)
        #pragma unroll
        for (int ct = 0; ct < 8; ++ct) acc[rt][ct] = (f32x4)0.f;

    #pragma unroll 1
    for (int s = 0; s < 8; ++s) {              // 8 x K=32
        half8 aF[4];
        #pragma unroll
        for (int rt = 0; rt < 4; ++rt) aF[rt] = cvt8(a0[rt], a1[rt]);  // RTN, == prep's cast
        if (s < 7) {
            #pragma unroll
            for (int rt = 0; rt < 4; ++rt) {
                const float4* ap = (const float4*)(abase + (size_t)(wid*64 + rt*16 + li) * DIM
                                                   + (s + 1) * 32 + lg*8);
                a0[rt] = ap[0]; a1[rt] = ap[1];
            }
        }
        int sbase = (s >> 1) * 16384;
        int kofs  = (s & 1) * 64;
        #pragma unroll
        for (int ct = 0; ct < 8; ++ct) {
            half8 bf = *(const half8*)((const char*)Bs + sbase + (ct*16 + li) * 128
                                       + ((kofs + lg*16) ^ swz));
            acc[0][ct] = __builtin_amdgcn_mfma_f32_16x16x32_f16(aF[0], bf, acc[0][ct], 0, 0, 0);
            acc[1][ct] = __builtin_amdgcn_mfma_f32_16x16x32_f16(aF[1], bf, acc[1][ct], 0, 0, 0);
            acc[2][ct] = __builtin_amdgcn_mfma_f32_16x16x32_f16(aF[2], bf, acc[2][ct], 0, 0, 0);
            acc[3][ct] = __builtin_amdgcn_mfma_f32_16x16x32_f16(aF[3], bf, acc[3][ct], 0, 0, 0);
        }
    }

    // u64-packed top-2 per row over this block's 128 codes (order == (dist, idx))
    #pragma unroll
    for (int rt = 0; rt < 4; ++rt) {
        #pragma unroll
        for (int q = 0; q < 4; ++q) {
            int rowl = wid*64 + rt*16 + lg*4 + q;
            float rvq = rv[rt][q];
            unsigned long long v1 = ~0ull, v2 = ~0ull;
            #pragma unroll
            for (int ct = 0; ct < 8; ++ct) {
                float dvf = fmaf(-2.0f, acc[rt][ct][q], rvq + cnv[ct]);
                unsigned long long x =
                    ((unsigned long long)__float_as_uint(dvf) << 32) |
                    (unsigned)(ccol0 + ct*16 + li);
                unsigned long long mn = x < v1 ? x : v1;
                unsigned long long mx = x < v1 ? v1 : x;
                v1 = mn;
                v2 = mx < v2 ? mx : v2;
            }
            #pragma unroll
            for (int m = 1; m <= 8; m <<= 1) {
                unsigned long long w1 = __shfl_xor(v1, m, 64);
                unsigned long long w2 = __shfl_xor(v2, m, 64);
                unsigned long long mn = v1 < w1 ? v1 : w1;
                unsigned long long mx = v1 < w1 ? w1 : v1;
                unsigned long long m2 = w2 < v2 ? w2 : v2;
                v1 = mn;
                v2 = mx < m2 ? mx : m2;
            }
            if (li == 0) {
                ulonglong2 o; o.x = v1; o.y = v2;
                part[(arow0 + rowl) * 8 + ctile] = o;
            }
        }
    }
}

// ============ kernel 3: gap-gated exact refinement + gather + histogram ============
__global__ __launch_bounds__(256) void vq_refine2(const float* __restrict__ z,
                                                  const float* __restrict__ cbk,
                                                  const float* __restrict__ rn,
                                                  const float* __restrict__ cn,
                                                  const ulonglong2* __restrict__ part,
                                                  int* __restrict__ hist,
                                                  float* __restrict__ zq) {
    __shared__ float4 zl[4][64];
    int wid = threadIdx.x >> 6;
    int row = blockIdx.x * 4 + wid;
    int l   = threadIdx.x & 63;

    unsigned long long vc = ~0ull;
    if (l < 16) {
        ulonglong2 P = part[(size_t)row * 8 + (l & 7)];
        vc = (l < 8) ? P.x : P.y;
    }
    unsigned long long v1 = vc, v2 = ~0ull;
    #pragma unroll
    for (int m = 1; m <= 8; m <<= 1) {
        unsigned long long w1 = __shfl_xor(v1, m, 64);
        unsigned long long w2 = __shfl_xor(v2, m, 64);
        unsigned long long mn = v1 < w1 ? v1 : w1;
        unsigned long long mx = v1 < w1 ? w1 : v1;
        unsigned long long m2 = w2 < v2 ? w2 : v2;
        v1 = mn;
        v2 = mx < m2 ? mx : m2;
    }
    v1 = __shfl(v1, 0, 64); v2 = __shfl(v2, 0, 64);
    float v1f = __uint_as_float((unsigned)(v1 >> 32));
    float v2f = __uint_as_float((unsigned)(v2 >> 32));

    int winner = (int)(v1 & 0xffffffffu);
    if (v2f - v1f <= TAU) {          // ambiguous: exact fp32 chain (proven rounding)
        zl[wid][l] = ((const float4*)(z + (size_t)row * DIM))[l];
        float vcf = __uint_as_float((unsigned)(vc >> 32));
        int   ic  = (int)(vc & 0xffffffffu);
        unsigned long long e = ~0ull;
        if (l < 16 && vcf <= v1f + TAU) {
            const float4* cr = (const float4*)(cbk + (size_t)ic * DIM);
            float dot = 0.f;
            #pragma unroll 8
            for (int d4 = 0; d4 < 64; ++d4) {
                float4 c4 = cr[d4];
                float4 z4 = zl[wid][d4];
                dot = fmaf(z4.x, c4.x, dot); dot = fmaf(z4.y, c4.y, dot);
                dot = fmaf(z4.z, c4.z, dot); dot = fmaf(z4.w, c4.w, dot);
            }
            float dv = (rn[row] + cn[ic]) - 2.0f * dot;
            e = ((unsigned long long)__float_as_uint(dv) << 32) | (unsigned)ic;
        }
        #pragma unroll
        for (int m = 1; m <= 8; m <<= 1) {
            unsigned long long w = __shfl_xor(e, m, 64);
            e = w < e ? w : e;
        }
        winner = (int)(__shfl(e, 0, 64) & 0xffffffffu);
    }

    float4 cv = ((const float4*)(cbk + (size_t)winner * DIM))[l];
    ((float4*)(zq + (size_t)row * DIM))[l] = cv;
    if (l == 0) atomicAdd(hist + winner, 1);
}

// ============ kernel 4: perplexity ============
__global__ __launch_bounds__(256) void vq_perp(const int* __restrict__ hist,
                                               float* __restrict__ out) {
    __shared__ float red[4];
    int tid = threadIdx.x;
    float s = 0.f;
    #pragma unroll
    for (int k = tid; k < KCODES; k += 256) {
        float avg = (float)hist[k] * (1.0f / 65536.0f);
        s += avg * logf(avg + 1e-10f);
    }
    #pragma unroll
    for (int m = 32; m; m >>= 1) s += __shfl_xor(s, m, 64);
    if ((tid & 63) == 0) red[tid >> 6] = s;
    __syncthreads();
    if (tid == 0) out[0] = expf(-(red[0] + red[1] + red[2] + red[3]));
}

// ============ launch ============
extern "C" void kernel_launch(void* const* d_in, const int* in_sizes, int n_in,
                              void* d_out, int out_size, void* d_ws, size_t ws_size,
                              hipStream_t stream) {
    const float* z  = (const float*)d_in[0];
    const float* cb = (const float*)d_in[1];
    float* zq   = (float*)d_out;
    float* perp = zq + (size_t)N_ROWS * DIM;

    _Float16*   B2  = (_Float16*)d_ws;                        // [1024][256] f16 (512 KB)
    float*      rn  = (float*)((char*)d_ws + 524288);         // 256 KB
    float*      cn  = (float*)((char*)d_ws + 786432);         // 4 KB
    int*        hist= (int*)((char*)d_ws + 790528);           // 4 KB
    ulonglong2* part= (ulonglong2*)((char*)d_ws + 794624);    // [65536][8] top-2 (8 MB)

    hipMemsetAsync(hist, 0, KCODES * sizeof(int), stream);
    vq_prep   <<<16640, 256, 0, stream>>>(z, cb, B2, rn, cn);
    vq_gemm3  <<<2048,  256, 0, stream>>>(z, B2, rn, cn, part);
    vq_refine2<<<16384, 256, 0, stream>>>(z, cb, rn, cn, part, hist, zq);
    vq_perp   <<<1,     256, 0, stream>>>(hist, perp);
}